// Round 1
// 438.901 us; speedup vs baseline: 1.0536x; 1.0536x over previous
//
#include <hip/hip_runtime.h>

// RPDC depthwise sparse-5x5 (pixel-difference) conv.
// x: (16,256,128,128) fp32, weight: (256,1,3,3) fp32, out same shape.
//
// out(h,w) = t0*(A[w-2]-B[w-1]) + t1*(A[w]-B[w]) + t2*(A[w+2]-B[w+1])
//          + t3*(C[w-2]-C[w-1]) + t4*(C[w+2]-C[w+1])
//          + t5*(E[w-2]-D[w-1]) + t6*(E[w]-D[w]) + t7*(E[w+2]-D[w+1])
// A..E = rows h-2..h+2 (zero pad), tj = weight flat [1+j].
//
// v2 strategy (latency-bound fix): one thread owns a float4 column group
// (4 cols) and a 32-row H-chunk. Per row: 3 vector loads (float2|float4|float2
// covering cols w0-2..w0+5, all 8B/16B aligned) + 1 float4 store.
// 6-row x 8-col register ring, 2-stage load pipeline (issue at h, insert at
// h+1, consume at h+2), fully unrolled -> no rotation moves, deep MLP.

#define HH 128
#define WW 128
#define CHUNK 32               // rows per thread-strip
#define SPB 8                  // strips per 256-thread block

__global__ __launch_bounds__(256, 4) void rpdc_kernel(
    const float* __restrict__ x, const float* __restrict__ wt,
    float* __restrict__ out, int C)
{
    const int tid   = threadIdx.x;
    const int l     = tid & 31;                      // col-group lane (4 cols each)
    const int s     = blockIdx.x * SPB + (tid >> 5); // strip = (plane, chunk)
    const int plane = s >> 2;                        // n*C + c
    const int h0    = (s & 3) * CHUNK;
    const int c     = plane & (C - 1);               // C = 256 (pow2)

    const float* wp = wt + (size_t)c * 9;
    const float t0 = wp[1], t1 = wp[2], t2 = wp[3], t3 = wp[4];
    const float t4 = wp[5], t5 = wp[6], t6 = wp[7], t7 = wp[8];

    const int w0  = l * 4;                            // first owned column
    // halo load offsets (aligned: olp is 8B-aligned, orp is 8B/16B-aligned)
    const int olp = (l == 0) ? 0 : (w0 - 2);          // cols w0-2, w0-1
    const int orp = (l == 31) ? (w0 + 2) : (w0 + 4);  // cols w0+4, w0+5
    const float ml = (l == 0) ? 0.f : 1.f;            // zero-pad masks
    const float mr = (l == 31) ? 0.f : 1.f;

    const float* xb = x + (size_t)plane * (HH * WW) + (size_t)h0 * WW; // row h0
    float* ob = out + (size_t)plane * (HH * WW) + (size_t)h0 * WW + w0;

    // ring[k] holds relative row rr where slot = (rr + 2) % 6, 8 cols w0-2..w0+5
    float ring[6][8];
    float2 tl, tr; float4 tv;   // staged loads (row rr = h+3 at loop iter h)

    auto issue = [&](int rr, float2& a, float4& v, float2& b) {
        const int r = h0 + rr;                 // absolute row
        if ((unsigned)r < (unsigned)HH) {      // half-wave-uniform branch
            const float* p = xb + rr * WW;
            a = *(const float2*)(p + olp);
            v = *(const float4*)(p + w0);
            b = *(const float2*)(p + orp);
        } else {                               // zero pad above/below
            a = make_float2(0.f, 0.f);
            v = make_float4(0.f, 0.f, 0.f, 0.f);
            b = make_float2(0.f, 0.f);
        }
    };
    auto insert = [&](float (&row)[8], const float2& a, const float4& v,
                      const float2& b) {
        row[0] = a.x * ml; row[1] = a.y * ml;
        row[2] = v.x; row[3] = v.y; row[4] = v.z; row[5] = v.w;
        row[6] = b.x * mr; row[7] = b.y * mr;
    };

    // prologue: rows rr = -2..+2 into slots 0..4, stage rr = +3
#pragma unroll
    for (int k = 0; k < 5; ++k) {
        float2 a, b; float4 v;
        issue(k - 2, a, v, b);
        insert(ring[k], a, v, b);
    }
    issue(3, tl, tv, tr);

#pragma unroll
    for (int h = 0; h < CHUNK; ++h) {
        // stage-1: issue loads for rr = h+4 (consumed at iter h+2).
        // last 2 iters need no new rows -> force OOB (compile-time folded).
        float2 nl, nr; float4 nv;
        issue(h < CHUNK - 2 ? h + 4 : HH, nl, nv, nr);

        // stage-2: mask + insert previously loaded row rr = h+3
        insert(ring[(h + 5) % 6], tl, tv, tr);

        const float (&A)[8]  = ring[h % 6];        // rr h-2
        const float (&B)[8]  = ring[(h + 1) % 6];  // rr h-1
        const float (&Cc)[8] = ring[(h + 2) % 6];  // rr h
        const float (&D)[8]  = ring[(h + 3) % 6];  // rr h+1
        const float (&E)[8]  = ring[(h + 4) % 6];  // rr h+2

        float o[4];
#pragma unroll
        for (int j = 0; j < 4; ++j) {              // arr[k] = col w0-2+k
            float r = t0 * (A[j]     - B[j + 1]);
            r      += t1 * (A[j + 2] - B[j + 2]);
            r      += t2 * (A[j + 4] - B[j + 3]);
            r      += t3 * (Cc[j]     - Cc[j + 1]);
            r      += t4 * (Cc[j + 4] - Cc[j + 3]);
            r      += t5 * (E[j]     - D[j + 1]);
            r      += t6 * (E[j + 2] - D[j + 2]);
            r      += t7 * (E[j + 4] - D[j + 3]);
            o[j] = r;
        }
        *(float4*)(ob + h * WW) = make_float4(o[0], o[1], o[2], o[3]);

        tl = nl; tv = nv; tr = nr;   // advance pipeline (renamed by unroll)
    }
}

extern "C" void kernel_launch(void* const* d_in, const int* in_sizes, int n_in,
                              void* d_out, int out_size, void* d_ws, size_t ws_size,
                              hipStream_t stream) {
    const float* x = (const float*)d_in[0];
    const float* wt = (const float*)d_in[1];
    float* out = (float*)d_out;

    const int C = in_sizes[1] / 9;                 // 256
    const int planes = in_sizes[0] / (HH * WW);    // N*C = 4096

    // strips = planes * (HH/CHUNK); 8 strips (2 planes) per 256-thread block
    dim3 grid(planes * (HH / CHUNK) / SPB);        // 2048
    dim3 block(256);
    rpdc_kernel<<<grid, block, 0, stream>>>(x, wt, out, C);
}